// Round 1
// baseline (1638.277 us; speedup 1.0000x reference)
//
#include <hip/hip_runtime.h>
#include <math.h>

// Problem constants
#define BQ 2
#define LQ 2048
#define DQ 1024
#define HQ 16
#define HDQ 64

// ---------------- GEMM: 128x128 tile, BK=16, 256 threads, 8x8 micro-tile ----
#define GBM 128
#define GBN 128
#define GBK 16

// MODE 0: qkv projection -> scatter to q/k/v ws in [B,H,L,HD] layout
// MODE 1: out projection -> add bias, write row-major [M,N] to o0
template<int MODE>
__global__ __launch_bounds__(256) void gemm_kernel(
    const float* __restrict__ A, const float* __restrict__ W,
    int M, int N, int K,
    float* __restrict__ o0, float* __restrict__ o1, float* __restrict__ o2,
    const float* __restrict__ bias)
{
    __shared__ float As[GBK][GBM + 4];   // [k][m], pad 4 keeps 16B align + kills store conflicts
    __shared__ float Bs[GBK][GBN];       // [k][n]
    const int tid = threadIdx.x;
    const int m0 = blockIdx.y * GBM;
    const int n0 = blockIdx.x * GBN;
    const int tx = tid & 15;   // n dir
    const int ty = tid >> 4;   // m dir

    float acc[8][8];
#pragma unroll
    for (int i = 0; i < 8; i++)
#pragma unroll
        for (int j = 0; j < 8; j++) acc[i][j] = 0.f;

    for (int k0 = 0; k0 < K; k0 += GBK) {
#pragma unroll
        for (int i = 0; i < 2; i++) {
            int idx = tid + i * 256;
            int r  = idx >> 2, kc = (idx & 3) * 4;           // A tile: 128 rows x 16 k
            float4 av = *(const float4*)(A + (size_t)(m0 + r) * K + k0 + kc);
            As[kc + 0][r] = av.x; As[kc + 1][r] = av.y;
            As[kc + 2][r] = av.z; As[kc + 3][r] = av.w;
            int rk = idx >> 5, nc = (idx & 31) * 4;          // B tile: 16 k x 128 n
            float4 bv = *(const float4*)(W + (size_t)(k0 + rk) * N + n0 + nc);
            *(float4*)(&Bs[rk][nc]) = bv;
        }
        __syncthreads();
#pragma unroll
        for (int kk = 0; kk < GBK; kk++) {
            float a[8], b[8];
            *(float4*)(&a[0]) = *(const float4*)(&As[kk][ty * 8]);
            *(float4*)(&a[4]) = *(const float4*)(&As[kk][ty * 8 + 4]);
            *(float4*)(&b[0]) = *(const float4*)(&Bs[kk][tx * 8]);
            *(float4*)(&b[4]) = *(const float4*)(&Bs[kk][tx * 8 + 4]);
#pragma unroll
            for (int i = 0; i < 8; i++)
#pragma unroll
                for (int j = 0; j < 8; j++)
                    acc[i][j] = fmaf(a[i], b[j], acc[i][j]);
        }
        __syncthreads();
    }

    if (MODE == 0) {
        // column block of 8 stays within one head (64 | n0, 8 | tx*8)
        const int nbase = n0 + tx * 8;
        const int which = nbase >> 10;          // 0=q 1=k 2=v
        const int h = (nbase >> 6) & 15;
        const int d = nbase & 63;
        float* dst = (which == 0) ? o0 : ((which == 1) ? o1 : o2);
#pragma unroll
        for (int i = 0; i < 8; i++) {
            int m = m0 + ty * 8 + i;
            int b = m >> 11, l = m & 2047;
            float* p = dst + (((size_t)(b * HQ + h) * LQ + l) * HDQ + d);
            *(float4*)(p)     = make_float4(acc[i][0], acc[i][1], acc[i][2], acc[i][3]);
            *(float4*)(p + 4) = make_float4(acc[i][4], acc[i][5], acc[i][6], acc[i][7]);
        }
    } else {
        const int nbase = n0 + tx * 8;
        float bj[8];
#pragma unroll
        for (int j = 0; j < 8; j++) bj[j] = bias[nbase + j];
#pragma unroll
        for (int i = 0; i < 8; i++) {
            int m = m0 + ty * 8 + i;
            float* p = o0 + (size_t)m * N + nbase;
            *(float4*)(p)     = make_float4(acc[i][0] + bj[0], acc[i][1] + bj[1],
                                            acc[i][2] + bj[2], acc[i][3] + bj[3]);
            *(float4*)(p + 4) = make_float4(acc[i][4] + bj[4], acc[i][5] + bj[5],
                                            acc[i][6] + bj[6], acc[i][7] + bj[7]);
        }
    }
}

// ---------------- RoPE (in-place on q_ws and k_ws, which are contiguous) ----
__global__ __launch_bounds__(256) void rope_kernel(
    float* qk_ws, const float* __restrict__ cosT, const float* __restrict__ sinT)
{
    int idx = blockIdx.x * 256 + threadIdx.x;       // 2*B*H*L*32 total
    int d = idx & 31;
    int l = (idx >> 5) & (LQ - 1);
    float* base = qk_ws + (size_t)(idx >> 16) * (LQ * 64) + (size_t)l * 64;
    float c = cosT[l * 64 + d];
    float s = sinT[l * 64 + d];
    float v1 = base[d], v2 = base[d + 32];
    base[d]      = v1 * c - v2 * s;
    base[d + 32] = v2 * c + v1 * s;
}

// ---------------- causal flash attention: 64 q-rows x 32 k-cols per tile ----
__global__ __launch_bounds__(256) void attn_kernel(
    const float* __restrict__ q_ws, const float* __restrict__ k_ws,
    const float* __restrict__ v_ws, float* __restrict__ o_ws)
{
    __shared__ float qs_t[64][65];   // [d][r]  pad -> conflict-free stores+reads
    __shared__ float ks_t[64][33];   // [d][c]
    __shared__ float vs[32][64];     // [c][d]  uniform-c b128 broadcast reads
    __shared__ float ss_t[32][64];   // [c][r]  scores then p; lane-consecutive r
    __shared__ float m_s[64], l_s[64], al_s[64];

    const int tid = threadIdx.x;
    const int qt  = blockIdx.x;      // 0..31 (64 q rows each)
    const int bh  = blockIdx.y;      // 0..31
    const float scale = 0.125f;      // 1/sqrt(64)

    const float* qbase = q_ws + ((size_t)bh * LQ + qt * 64) * 64;
#pragma unroll
    for (int i = 0; i < 4; i++) {
        int idx = tid + i * 256;
        int r = idx >> 4, c4 = (idx & 15) * 4;
        float4 v4 = *(const float4*)(qbase + r * 64 + c4);
        qs_t[c4 + 0][r] = v4.x; qs_t[c4 + 1][r] = v4.y;
        qs_t[c4 + 2][r] = v4.z; qs_t[c4 + 3][r] = v4.w;
    }
    if (tid < 64) { m_s[tid] = -INFINITY; l_s[tid] = 0.f; }

    float o_acc[16];
#pragma unroll
    for (int i = 0; i < 16; i++) o_acc[i] = 0.f;

    const int r_o = tid >> 2;            // O row
    const int dg  = (tid & 3) * 16;      // O d-group
    const int tr  = (tid & 15) * 4;      // S rows (4)
    const int tc  = (tid >> 4) * 2;      // S cols (2)
    const int nkt = 2 * qt + 2;          // 32-key tiles covering 0..qt*64+63

    for (int kt = 0; kt < nkt; kt++) {
        const float* kb = k_ws + ((size_t)bh * LQ + kt * 32) * 64;
        const float* vb = v_ws + ((size_t)bh * LQ + kt * 32) * 64;
        __syncthreads();   // prior iter's O-update reads done before overwrite
#pragma unroll
        for (int i = 0; i < 2; i++) {
            int idx = tid + i * 256;
            int rr = idx >> 4, c4 = (idx & 15) * 4;
            float4 kv = *(const float4*)(kb + rr * 64 + c4);
            ks_t[c4 + 0][rr] = kv.x; ks_t[c4 + 1][rr] = kv.y;
            ks_t[c4 + 2][rr] = kv.z; ks_t[c4 + 3][rr] = kv.w;
            float4 vv = *(const float4*)(vb + rr * 64 + c4);
            *(float4*)(&vs[rr][c4]) = vv;
        }
        __syncthreads();

        // S = Q K^T for 4x2 micro-tile
        float sv[4][2];
#pragma unroll
        for (int i = 0; i < 4; i++) { sv[i][0] = 0.f; sv[i][1] = 0.f; }
#pragma unroll 16
        for (int d = 0; d < 64; d++) {
            float b0 = ks_t[d][tc + 0];
            float b1 = ks_t[d][tc + 1];
#pragma unroll
            for (int i = 0; i < 4; i++) {
                float a = qs_t[d][tr + i];
                sv[i][0] = fmaf(a, b0, sv[i][0]);
                sv[i][1] = fmaf(a, b1, sv[i][1]);
            }
        }
#pragma unroll
        for (int i = 0; i < 4; i++) {
            int gq = qt * 64 + tr + i;
#pragma unroll
            for (int j = 0; j < 2; j++) {
                int gk = kt * 32 + tc + j;
                float x = sv[i][j] * scale;
                ss_t[tc + j][tr + i] = (gk > gq) ? -INFINITY : x;
            }
        }
        __syncthreads();

        // online softmax row pass (wave 0)
        if (tid < 64) {
            float mold = m_s[tid];
            float tmax = -INFINITY;
#pragma unroll 8
            for (int c = 0; c < 32; c++) tmax = fmaxf(tmax, ss_t[c][tid]);
            float mnew = fmaxf(mold, tmax);
            float alpha = __expf(mold - mnew);   // mold=-inf -> 0
            float psum = 0.f;
#pragma unroll 8
            for (int c = 0; c < 32; c++) {
                float p = __expf(ss_t[c][tid] - mnew);
                ss_t[c][tid] = p;
                psum += p;
            }
            l_s[tid]  = l_s[tid] * alpha + psum;
            m_s[tid]  = mnew;
            al_s[tid] = alpha;
        }
        __syncthreads();

        // O += P V
        float al = al_s[r_o];
#pragma unroll
        for (int i = 0; i < 16; i++) o_acc[i] *= al;
#pragma unroll 8
        for (int c = 0; c < 32; c++) {
            float p = ss_t[c][r_o];
            float4 w0 = *(const float4*)(&vs[c][dg]);
            float4 w1 = *(const float4*)(&vs[c][dg + 4]);
            float4 w2 = *(const float4*)(&vs[c][dg + 8]);
            float4 w3 = *(const float4*)(&vs[c][dg + 12]);
            o_acc[0]  = fmaf(p, w0.x, o_acc[0]);  o_acc[1]  = fmaf(p, w0.y, o_acc[1]);
            o_acc[2]  = fmaf(p, w0.z, o_acc[2]);  o_acc[3]  = fmaf(p, w0.w, o_acc[3]);
            o_acc[4]  = fmaf(p, w1.x, o_acc[4]);  o_acc[5]  = fmaf(p, w1.y, o_acc[5]);
            o_acc[6]  = fmaf(p, w1.z, o_acc[6]);  o_acc[7]  = fmaf(p, w1.w, o_acc[7]);
            o_acc[8]  = fmaf(p, w2.x, o_acc[8]);  o_acc[9]  = fmaf(p, w2.y, o_acc[9]);
            o_acc[10] = fmaf(p, w2.z, o_acc[10]); o_acc[11] = fmaf(p, w2.w, o_acc[11]);
            o_acc[12] = fmaf(p, w3.x, o_acc[12]); o_acc[13] = fmaf(p, w3.y, o_acc[13]);
            o_acc[14] = fmaf(p, w3.z, o_acc[14]); o_acc[15] = fmaf(p, w3.w, o_acc[15]);
        }
    }

    // write O / l  -> [B, L, H*HD]
    float invl = 1.0f / l_s[r_o];
    int b = bh >> 4, h = bh & 15;
    int gq = qt * 64 + r_o;
    float* op = o_ws + ((size_t)(b * LQ + gq)) * 1024 + h * 64 + dg;
#pragma unroll
    for (int i = 0; i < 16; i += 4) {
        *(float4*)(op + i) = make_float4(o_acc[i] * invl, o_acc[i + 1] * invl,
                                         o_acc[i + 2] * invl, o_acc[i + 3] * invl);
    }
}

// ---------------- launch -----------------------------------------------------
extern "C" void kernel_launch(void* const* d_in, const int* in_sizes, int n_in,
                              void* d_out, int out_size, void* d_ws, size_t ws_size,
                              hipStream_t stream) {
    const float* x        = (const float*)d_in[0];
    const float* rope_cos = (const float*)d_in[1];
    const float* rope_sin = (const float*)d_in[2];
    const float* W_qkv    = (const float*)d_in[3];
    const float* W_out    = (const float*)d_in[4];
    const float* b_out    = (const float*)d_in[5];
    float* out = (float*)d_out;

    // workspace: q,k,v in [B,H,L,HD] (4M floats each) + attn out [B,L,H*HD] (4M) = 64 MB
    float* ws   = (float*)d_ws;
    float* q_ws = ws;
    float* k_ws = ws + (size_t)4 * 1024 * 1024;
    float* v_ws = ws + (size_t)8 * 1024 * 1024;
    float* o_ws = ws + (size_t)12 * 1024 * 1024;

    dim3 g1(3072 / GBN, 4096 / GBM);
    gemm_kernel<0><<<g1, 256, 0, stream>>>(x, W_qkv, 4096, 3072, 1024,
                                           q_ws, k_ws, v_ws, nullptr);

    rope_kernel<<<(2 * BQ * HQ * LQ * 32) / 256, 256, 0, stream>>>(q_ws, rope_cos, rope_sin);

    dim3 g2(32, 32);   // (q-tiles, B*H)
    attn_kernel<<<g2, 256, 0, stream>>>(q_ws, k_ws, v_ws, o_ws);

    dim3 g3(1024 / GBN, 4096 / GBM);
    gemm_kernel<1><<<g3, 256, 0, stream>>>(o_ws, W_out, 4096, 1024, 1024,
                                           out, nullptr, nullptr, b_out);
}

// Round 2
// 613.632 us; speedup vs baseline: 2.6698x; 2.6698x over previous
//
#include <hip/hip_runtime.h>
#include <math.h>

// Problem constants
#define BQ 2
#define LQ 2048
#define DQ 1024
#define HQ 16
#define HDQ 64

typedef __bf16 bf16_t;
typedef bf16_t bf16x4 __attribute__((ext_vector_type(4)));
typedef bf16_t bf16x8 __attribute__((ext_vector_type(8)));
typedef float f32x4 __attribute__((ext_vector_type(4)));

// ---------------- GEMM: 128x128 tile, BK=16, 256 threads, 8x8 micro-tile ----
#define GBM 128
#define GBN 128
#define GBK 16

// MODE 0: qkv projection -> scatter to q/k/v ws in [B,H,L,HD] layout
// MODE 1: out projection -> add bias, write row-major [M,N] to o0
template<int MODE>
__global__ __launch_bounds__(256) void gemm_kernel(
    const float* __restrict__ A, const float* __restrict__ W,
    int M, int N, int K,
    float* __restrict__ o0, float* __restrict__ o1, float* __restrict__ o2,
    const float* __restrict__ bias)
{
    __shared__ float As[GBK][GBM + 4];
    __shared__ float Bs[GBK][GBN];
    const int tid = threadIdx.x;
    const int m0 = blockIdx.y * GBM;
    const int n0 = blockIdx.x * GBN;
    const int tx = tid & 15;   // n dir
    const int ty = tid >> 4;   // m dir

    float acc[8][8];
#pragma unroll
    for (int i = 0; i < 8; i++)
#pragma unroll
        for (int j = 0; j < 8; j++) acc[i][j] = 0.f;

    for (int k0 = 0; k0 < K; k0 += GBK) {
#pragma unroll
        for (int i = 0; i < 2; i++) {
            int idx = tid + i * 256;
            int r  = idx >> 2, kc = (idx & 3) * 4;
            float4 av = *(const float4*)(A + (size_t)(m0 + r) * K + k0 + kc);
            As[kc + 0][r] = av.x; As[kc + 1][r] = av.y;
            As[kc + 2][r] = av.z; As[kc + 3][r] = av.w;
            int rk = idx >> 5, nc = (idx & 31) * 4;
            float4 bv = *(const float4*)(W + (size_t)(k0 + rk) * N + n0 + nc);
            *(float4*)(&Bs[rk][nc]) = bv;
        }
        __syncthreads();
#pragma unroll
        for (int kk = 0; kk < GBK; kk++) {
            float a[8], b[8];
            *(float4*)(&a[0]) = *(const float4*)(&As[kk][ty * 8]);
            *(float4*)(&a[4]) = *(const float4*)(&As[kk][ty * 8 + 4]);
            *(float4*)(&b[0]) = *(const float4*)(&Bs[kk][tx * 8]);
            *(float4*)(&b[4]) = *(const float4*)(&Bs[kk][tx * 8 + 4]);
#pragma unroll
            for (int i = 0; i < 8; i++)
#pragma unroll
                for (int j = 0; j < 8; j++)
                    acc[i][j] = fmaf(a[i], b[j], acc[i][j]);
        }
        __syncthreads();
    }

    if (MODE == 0) {
        const int nbase = n0 + tx * 8;
        const int which = nbase >> 10;          // 0=q 1=k 2=v
        const int h = (nbase >> 6) & 15;
        const int d = nbase & 63;
        float* dst = (which == 0) ? o0 : ((which == 1) ? o1 : o2);
#pragma unroll
        for (int i = 0; i < 8; i++) {
            int m = m0 + ty * 8 + i;
            int b = m >> 11, l = m & 2047;
            float* p = dst + (((size_t)(b * HQ + h) * LQ + l) * HDQ + d);
            *(float4*)(p)     = make_float4(acc[i][0], acc[i][1], acc[i][2], acc[i][3]);
            *(float4*)(p + 4) = make_float4(acc[i][4], acc[i][5], acc[i][6], acc[i][7]);
        }
    } else {
        const int nbase = n0 + tx * 8;
        float bj[8];
#pragma unroll
        for (int j = 0; j < 8; j++) bj[j] = bias[nbase + j];
#pragma unroll
        for (int i = 0; i < 8; i++) {
            int m = m0 + ty * 8 + i;
            float* p = o0 + (size_t)m * N + nbase;
            *(float4*)(p)     = make_float4(acc[i][0] + bj[0], acc[i][1] + bj[1],
                                            acc[i][2] + bj[2], acc[i][3] + bj[3]);
            *(float4*)(p + 4) = make_float4(acc[i][4] + bj[4], acc[i][5] + bj[5],
                                            acc[i][6] + bj[6], acc[i][7] + bj[7]);
        }
    }
}

// ---------------- RoPE (in-place on q_ws and k_ws, contiguous) --------------
__global__ __launch_bounds__(256) void rope_kernel(
    float* qk_ws, const float* __restrict__ cosT, const float* __restrict__ sinT)
{
    int idx = blockIdx.x * 256 + threadIdx.x;
    int d = idx & 31;
    int l = (idx >> 5) & (LQ - 1);
    float* base = qk_ws + (size_t)(idx >> 16) * (LQ * 64) + (size_t)l * 64;
    float c = cosT[l * 64 + d];
    float s = sinT[l * 64 + d];
    float v1 = base[d], v2 = base[d + 32];
    base[d]      = v1 * c - v2 * s;
    base[d + 32] = v2 * c + v1 * s;
}

// ---------------- bf16 MFMA flash attention ---------------------------------
// Block: 4 waves = 64 q rows of one (b,h). Paired q-tiles (p, 31-p) -> every
// block does exactly 33 kv-tiles of 64 keys. MFMA 16x16x32 bf16:
//   A[m=lane&15][k=quad*8+j], B[k=quad*8+j][n=lane&15], D col=lane&15 row=quad*4+reg
__global__ __launch_bounds__(256) void attn_mfma_kernel(
    const float* __restrict__ q_ws, const float* __restrict__ k_ws,
    const float* __restrict__ v_ws, float* __restrict__ o_ws)
{
    // +8 bf16 pad -> 144B row stride = 4-bank rotation: 2-way conflicts (free)
    __shared__ __align__(16) bf16_t Qb[64][72];
    __shared__ __align__(16) bf16_t Kb[64][72];
    __shared__ __align__(16) bf16_t Vt[64][72];     // [d][kv] (transposed)
    __shared__ __align__(16) bf16_t Pb[4][16][72];  // per-wave P round-trip

    const int tid  = threadIdx.x;
    const int lane = tid & 63;
    const int w    = tid >> 6;      // wave id: q-row strip [w*16, w*16+16)
    const int quad = lane >> 4;
    const int lr   = lane & 15;
    const int bh   = blockIdx.y;    // 0..31
    const int pair = blockIdx.x;    // 0..15
    const int vd   = tid & 63;      // V-transpose staging: d index
    const int vg   = tid >> 6;

    for (int phase = 0; phase < 2; phase++) {
        const int qt = (phase == 0) ? pair : 31 - pair;
        const float* qbase = q_ws + ((size_t)bh * LQ + qt * 64) * 64;

        __syncthreads();            // prior phase's LDS reads done
        // stage Q tile (64x64 fp32 -> bf16 LDS, row-major)
#pragma unroll
        for (int i = 0; i < 4; i++) {
            int idx = tid + i * 256;
            int r = idx >> 4, c4 = (idx & 15) * 4;
            float4 v = *(const float4*)(qbase + r * 64 + c4);
            bf16x4 bv; bv[0] = (bf16_t)v.x; bv[1] = (bf16_t)v.y;
            bv[2] = (bf16_t)v.z; bv[3] = (bf16_t)v.w;
            *(bf16x4*)(&Qb[r][c4]) = bv;
        }
        __syncthreads();
        const bf16x8 qa0 = *(const bf16x8*)(&Qb[w * 16 + lr][quad * 8]);
        const bf16x8 qa1 = *(const bf16x8*)(&Qb[w * 16 + lr][32 + quad * 8]);

        f32x4 Oacc[4];
#pragma unroll
        for (int nt = 0; nt < 4; nt++)
#pragma unroll
            for (int r = 0; r < 4; r++) Oacc[nt][r] = 0.f;
        float m_r[4] = {-INFINITY, -INFINITY, -INFINITY, -INFINITY};
        float l_r[4] = {0.f, 0.f, 0.f, 0.f};

        for (int kt = 0; kt <= qt; kt++) {
            const float* kb = k_ws + ((size_t)bh * LQ + kt * 64) * 64;
            const float* vb = v_ws + ((size_t)bh * LQ + kt * 64) * 64;
            __syncthreads();        // prior iter's Kb/Vt reads done
            // stage K row-major
#pragma unroll
            for (int i = 0; i < 4; i++) {
                int idx = tid + i * 256;
                int r = idx >> 4, c4 = (idx & 15) * 4;
                float4 v = *(const float4*)(kb + r * 64 + c4);
                bf16x4 bv; bv[0] = (bf16_t)v.x; bv[1] = (bf16_t)v.y;
                bv[2] = (bf16_t)v.z; bv[3] = (bf16_t)v.w;
                *(bf16x4*)(&Kb[r][c4]) = bv;
            }
            // stage V transposed: Vt[d][kv]; coalesced column reads
#pragma unroll
            for (int i = 0; i < 4; i++) {
                int kv0 = i * 16 + vg * 4;
                bf16x4 bv;
#pragma unroll
                for (int j = 0; j < 4; j++)
                    bv[j] = (bf16_t)vb[(size_t)(kv0 + j) * 64 + vd];
                *(bf16x4*)(&Vt[vd][kv0]) = bv;
            }
            __syncthreads();

            // S = Q K^T  (wave's 16 rows x 64 kv)
            f32x4 s[4];
#pragma unroll
            for (int nt = 0; nt < 4; nt++) {
                bf16x8 kb0 = *(const bf16x8*)(&Kb[nt * 16 + lr][quad * 8]);
                bf16x8 kb1 = *(const bf16x8*)(&Kb[nt * 16 + lr][32 + quad * 8]);
                f32x4 z = {0.f, 0.f, 0.f, 0.f};
                z = __builtin_amdgcn_mfma_f32_16x16x32_bf16(qa0, kb0, z, 0, 0, 0);
                z = __builtin_amdgcn_mfma_f32_16x16x32_bf16(qa1, kb1, z, 0, 0, 0);
                s[nt] = z;
            }
            // scale + causal mask (only diagonal tile needs masking)
            const bool diag = (kt == qt);
#pragma unroll
            for (int nt = 0; nt < 4; nt++)
#pragma unroll
                for (int r = 0; r < 4; r++) {
                    float x = s[nt][r] * 0.125f;
                    if (diag && (nt * 16 + lr > w * 16 + quad * 4 + r)) x = -INFINITY;
                    s[nt][r] = x;
                }
            // online softmax: rows owned by (quad, reg); reduce across 16 lanes
            float mx[4], al[4], rs[4];
#pragma unroll
            for (int r = 0; r < 4; r++) {
                float m = fmaxf(fmaxf(s[0][r], s[1][r]), fmaxf(s[2][r], s[3][r]));
                m = fmaxf(m, __shfl_xor(m, 1));
                m = fmaxf(m, __shfl_xor(m, 2));
                m = fmaxf(m, __shfl_xor(m, 4));
                m = fmaxf(m, __shfl_xor(m, 8));
                mx[r] = m;
            }
#pragma unroll
            for (int r = 0; r < 4; r++) {
                float mnew = fmaxf(m_r[r], mx[r]);
                al[r] = __expf(m_r[r] - mnew);
                m_r[r] = mnew;
            }
#pragma unroll
            for (int nt = 0; nt < 4; nt++)
#pragma unroll
                for (int r = 0; r < 4; r++)
                    s[nt][r] = __expf(s[nt][r] - m_r[r]);
#pragma unroll
            for (int r = 0; r < 4; r++) {
                float t = s[0][r] + s[1][r] + s[2][r] + s[3][r];
                t += __shfl_xor(t, 1);
                t += __shfl_xor(t, 2);
                t += __shfl_xor(t, 4);
                t += __shfl_xor(t, 8);
                rs[r] = t;
                l_r[r] = l_r[r] * al[r] + t;
            }
            (void)rs;
            // P: C-layout -> A-layout via wave-private LDS region
#pragma unroll
            for (int nt = 0; nt < 4; nt++)
#pragma unroll
                for (int r = 0; r < 4; r++)
                    Pb[w][quad * 4 + r][nt * 16 + lr] = (bf16_t)s[nt][r];
            __syncthreads();        // conservative: Pb visibility

            // O = O*alpha + P V
#pragma unroll
            for (int nt = 0; nt < 4; nt++)
#pragma unroll
                for (int r = 0; r < 4; r++) Oacc[nt][r] *= al[r];
            bf16x8 pa0 = *(const bf16x8*)(&Pb[w][lr][quad * 8]);
            bf16x8 pa1 = *(const bf16x8*)(&Pb[w][lr][32 + quad * 8]);
#pragma unroll
            for (int nt = 0; nt < 4; nt++) {
                bf16x8 vb0 = *(const bf16x8*)(&Vt[nt * 16 + lr][quad * 8]);
                bf16x8 vb1 = *(const bf16x8*)(&Vt[nt * 16 + lr][32 + quad * 8]);
                Oacc[nt] = __builtin_amdgcn_mfma_f32_16x16x32_bf16(pa0, vb0, Oacc[nt], 0, 0, 0);
                Oacc[nt] = __builtin_amdgcn_mfma_f32_16x16x32_bf16(pa1, vb1, Oacc[nt], 0, 0, 0);
            }
        }

        // epilogue: O / l -> o_ws [B, L, H*HD] fp32
        const int b = bh >> 4, h = bh & 15;
#pragma unroll
        for (int r = 0; r < 4; r++) {
            float inv = 1.0f / l_r[r];
            int q = qt * 64 + w * 16 + quad * 4 + r;
            float* op = o_ws + ((size_t)(b * LQ + q)) * 1024 + h * 64;
#pragma unroll
            for (int nt = 0; nt < 4; nt++)
                op[nt * 16 + lr] = Oacc[nt][r] * inv;
        }
    }
}

// ---------------- launch -----------------------------------------------------
extern "C" void kernel_launch(void* const* d_in, const int* in_sizes, int n_in,
                              void* d_out, int out_size, void* d_ws, size_t ws_size,
                              hipStream_t stream) {
    const float* x        = (const float*)d_in[0];
    const float* rope_cos = (const float*)d_in[1];
    const float* rope_sin = (const float*)d_in[2];
    const float* W_qkv    = (const float*)d_in[3];
    const float* W_out    = (const float*)d_in[4];
    const float* b_out    = (const float*)d_in[5];
    float* out = (float*)d_out;

    float* ws   = (float*)d_ws;
    float* q_ws = ws;
    float* k_ws = ws + (size_t)4 * 1024 * 1024;
    float* v_ws = ws + (size_t)8 * 1024 * 1024;
    float* o_ws = ws + (size_t)12 * 1024 * 1024;

    dim3 g1(3072 / GBN, 4096 / GBM);
    gemm_kernel<0><<<g1, 256, 0, stream>>>(x, W_qkv, 4096, 3072, 1024,
                                           q_ws, k_ws, v_ws, nullptr);

    rope_kernel<<<(2 * BQ * HQ * LQ * 32) / 256, 256, 0, stream>>>(q_ws, rope_cos, rope_sin);

    dim3 g2(16, 32);   // (q-tile pairs, B*H) — balanced: 33 kv-tiles/block
    attn_mfma_kernel<<<g2, 256, 0, stream>>>(q_ws, k_ws, v_ws, o_ws);

    dim3 g3(1024 / GBN, 4096 / GBM);
    gemm_kernel<1><<<g3, 256, 0, stream>>>(o_ws, W_out, 4096, 1024, 1024,
                                           out, nullptr, nullptr, b_out);
}

// Round 3
// 253.853 us; speedup vs baseline: 6.4537x; 2.4173x over previous
//
#include <hip/hip_runtime.h>
#include <math.h>

// Problem constants
#define BQ 2
#define LQ 2048
#define DQ 1024
#define HQ 16
#define HDQ 64

typedef __bf16 bf16_t;
typedef bf16_t bf16x4 __attribute__((ext_vector_type(4)));
typedef bf16_t bf16x8 __attribute__((ext_vector_type(8)));
typedef float f32x4 __attribute__((ext_vector_type(4)));

// async global->LDS, 16B per lane; LDS dest = wave-uniform base + lane*16
__device__ __forceinline__ void gld16(const void* g, void* l) {
    __builtin_amdgcn_global_load_lds(
        (const __attribute__((address_space(1))) void*)g,
        (__attribute__((address_space(3))) void*)l, 16, 0, 0);
}

// ---------------- fp32 -> bf16 convert (x) ----------------------------------
__global__ __launch_bounds__(256) void convert_kernel(
    const float* __restrict__ in, bf16_t* __restrict__ out)
{
    int i = (blockIdx.x * 256 + threadIdx.x) * 4;
    float4 v = *(const float4*)(in + i);
    bf16x4 o;
    o[0] = (bf16_t)v.x; o[1] = (bf16_t)v.y; o[2] = (bf16_t)v.z; o[3] = (bf16_t)v.w;
    *(bf16x4*)(out + i) = o;
}

// ---------------- fp32 [K,N] -> bf16 [N,K] transpose-convert ----------------
__global__ __launch_bounds__(256) void transpose_bf16_kernel(
    const float* __restrict__ in, bf16_t* __restrict__ out, int K, int N)
{
    __shared__ float t[32][33];
    const int k0 = blockIdx.y * 32, n0 = blockIdx.x * 32;
    const int r = threadIdx.x >> 3, c4 = (threadIdx.x & 7) * 4;
    float4 v = *(const float4*)(in + (size_t)(k0 + r) * N + n0 + c4);
    t[r][c4 + 0] = v.x; t[r][c4 + 1] = v.y; t[r][c4 + 2] = v.z; t[r][c4 + 3] = v.w;
    __syncthreads();
    bf16x4 o;
    o[0] = (bf16_t)t[c4 + 0][r]; o[1] = (bf16_t)t[c4 + 1][r];
    o[2] = (bf16_t)t[c4 + 2][r]; o[3] = (bf16_t)t[c4 + 3][r];
    *(bf16x4*)(out + (size_t)(n0 + r) * K + k0 + c4) = o;
}

// ---------------- bf16 MFMA GEMM (m97 structure) ----------------------------
// A [M,K] bf16 row-major, Bt [N,K] bf16 row-major (transposed weights).
// 128x128 tile, BK=32, 4 waves each 64x64 via 4x4 MFMA 16x16x32.
// MODE 0: scatter fp32 q/k/v in [B,H,L,HD]. MODE 1: +bias, fp32 [M,N].
template<int MODE>
__global__ __launch_bounds__(256) void mfma_gemm_kernel(
    const bf16_t* __restrict__ A, const bf16_t* __restrict__ Bt,
    int M, int N, int K,
    float* __restrict__ o0, float* __restrict__ o1, float* __restrict__ o2,
    const float* __restrict__ bias)
{
    __shared__ __align__(16) bf16_t As[128][32];
    __shared__ __align__(16) bf16_t Bs[128][32];
    const int tid  = threadIdx.x;
    const int lane = tid & 63;
    const int w    = tid >> 6;
    const int lr   = lane & 15, quad = lane >> 4;
    const int wm   = w & 1, wn = w >> 1;
    const int m0   = blockIdx.y * 128, n0 = blockIdx.x * 128;
    const int srow = lane >> 2;       // staging row within 16-row group
    const int sch  = (lane & 3) * 8;  // staging k-chunk (8 bf16 = 16 B)

    f32x4 acc[4][4];
#pragma unroll
    for (int i = 0; i < 4; i++)
#pragma unroll
        for (int j = 0; j < 4; j++)
#pragma unroll
            for (int r = 0; r < 4; r++) acc[i][j][r] = 0.f;

    for (int k0 = 0; k0 < K; k0 += 32) {
        __syncthreads();   // prior iter's fragment reads complete
#pragma unroll
        for (int j = 0; j < 2; j++) {
            const int g = w * 2 + j;                 // 16-row group 0..7
            const int rr = g * 16 + srow;
            gld16(A  + (size_t)(m0 + rr) * K + k0 + sch, &As[g * 16][0]);
            gld16(Bt + (size_t)(n0 + rr) * K + k0 + sch, &Bs[g * 16][0]);
        }
        __syncthreads();   // drains vmcnt(0): LDS tiles complete

        bf16x8 af[4], bfr[4];
#pragma unroll
        for (int t = 0; t < 4; t++) {
            af[t]  = *(const bf16x8*)(&As[wm * 64 + t * 16 + lr][quad * 8]);
            bfr[t] = *(const bf16x8*)(&Bs[wn * 64 + t * 16 + lr][quad * 8]);
        }
#pragma unroll
        for (int mt = 0; mt < 4; mt++)
#pragma unroll
            for (int nt = 0; nt < 4; nt++)
                acc[mt][nt] = __builtin_amdgcn_mfma_f32_16x16x32_bf16(
                    af[mt], bfr[nt], acc[mt][nt], 0, 0, 0);
    }

    // epilogue: D col = lane&15 (n), row = quad*4 + r (m)
    if (MODE == 0) {
#pragma unroll
        for (int nt = 0; nt < 4; nt++) {
            const int n = n0 + wn * 64 + nt * 16 + lr;
            const int which = n >> 10;               // 0=q 1=k 2=v
            const int h = (n >> 6) & 15, d = n & 63;
            float* dst = (which == 0) ? o0 : ((which == 1) ? o1 : o2);
#pragma unroll
            for (int mt = 0; mt < 4; mt++)
#pragma unroll
                for (int r = 0; r < 4; r++) {
                    const int m = m0 + wm * 64 + mt * 16 + quad * 4 + r;
                    const int b = m >> 11, l = m & 2047;
                    dst[(((size_t)(b * HQ + h) * LQ + l) * HDQ + d)] = acc[mt][nt][r];
                }
        }
    } else {
#pragma unroll
        for (int nt = 0; nt < 4; nt++) {
            const int n = n0 + wn * 64 + nt * 16 + lr;
            const float bj = bias[n];
#pragma unroll
            for (int mt = 0; mt < 4; mt++)
#pragma unroll
                for (int r = 0; r < 4; r++) {
                    const int m = m0 + wm * 64 + mt * 16 + quad * 4 + r;
                    o0[(size_t)m * N + n] = acc[mt][nt][r] + bj;
                }
        }
    }
}

// ---------------- RoPE (in-place fp32 on q_ws,k_ws contiguous) --------------
__global__ __launch_bounds__(256) void rope_kernel(
    float* qk_ws, const float* __restrict__ cosT, const float* __restrict__ sinT)
{
    int idx = blockIdx.x * 256 + threadIdx.x;
    int d = idx & 31;
    int l = (idx >> 5) & (LQ - 1);
    float* base = qk_ws + (size_t)(idx >> 16) * (LQ * 64) + (size_t)l * 64;
    float c = cosT[l * 64 + d];
    float s = sinT[l * 64 + d];
    float v1 = base[d], v2 = base[d + 32];
    base[d]      = v1 * c - v2 * s;
    base[d + 32] = v2 * c + v1 * s;
}

// ---------------- bf16 MFMA flash attention (epilogue now writes bf16) -----
__global__ __launch_bounds__(256) void attn_mfma_kernel(
    const float* __restrict__ q_ws, const float* __restrict__ k_ws,
    const float* __restrict__ v_ws, bf16_t* __restrict__ o_ws)
{
    __shared__ __align__(16) bf16_t Qb[64][72];
    __shared__ __align__(16) bf16_t Kb[64][72];
    __shared__ __align__(16) bf16_t Vt[64][72];     // [d][kv]
    __shared__ __align__(16) bf16_t Pb[4][16][72];

    const int tid  = threadIdx.x;
    const int lane = tid & 63;
    const int w    = tid >> 6;
    const int quad = lane >> 4;
    const int lr   = lane & 15;
    const int bh   = blockIdx.y;
    const int pair = blockIdx.x;
    const int vd   = tid & 63;
    const int vg   = tid >> 6;

    for (int phase = 0; phase < 2; phase++) {
        const int qt = (phase == 0) ? pair : 31 - pair;
        const float* qbase = q_ws + ((size_t)bh * LQ + qt * 64) * 64;

        __syncthreads();
#pragma unroll
        for (int i = 0; i < 4; i++) {
            int idx = tid + i * 256;
            int r = idx >> 4, c4 = (idx & 15) * 4;
            float4 v = *(const float4*)(qbase + r * 64 + c4);
            bf16x4 bv; bv[0] = (bf16_t)v.x; bv[1] = (bf16_t)v.y;
            bv[2] = (bf16_t)v.z; bv[3] = (bf16_t)v.w;
            *(bf16x4*)(&Qb[r][c4]) = bv;
        }
        __syncthreads();
        const bf16x8 qa0 = *(const bf16x8*)(&Qb[w * 16 + lr][quad * 8]);
        const bf16x8 qa1 = *(const bf16x8*)(&Qb[w * 16 + lr][32 + quad * 8]);

        f32x4 Oacc[4];
#pragma unroll
        for (int nt = 0; nt < 4; nt++)
#pragma unroll
            for (int r = 0; r < 4; r++) Oacc[nt][r] = 0.f;
        float m_r[4] = {-INFINITY, -INFINITY, -INFINITY, -INFINITY};
        float l_r[4] = {0.f, 0.f, 0.f, 0.f};

        for (int kt = 0; kt <= qt; kt++) {
            const float* kb = k_ws + ((size_t)bh * LQ + kt * 64) * 64;
            const float* vb = v_ws + ((size_t)bh * LQ + kt * 64) * 64;
            __syncthreads();
#pragma unroll
            for (int i = 0; i < 4; i++) {
                int idx = tid + i * 256;
                int r = idx >> 4, c4 = (idx & 15) * 4;
                float4 v = *(const float4*)(kb + r * 64 + c4);
                bf16x4 bv; bv[0] = (bf16_t)v.x; bv[1] = (bf16_t)v.y;
                bv[2] = (bf16_t)v.z; bv[3] = (bf16_t)v.w;
                *(bf16x4*)(&Kb[r][c4]) = bv;
            }
#pragma unroll
            for (int i = 0; i < 4; i++) {
                int kv0 = i * 16 + vg * 4;
                bf16x4 bv;
#pragma unroll
                for (int j = 0; j < 4; j++)
                    bv[j] = (bf16_t)vb[(size_t)(kv0 + j) * 64 + vd];
                *(bf16x4*)(&Vt[vd][kv0]) = bv;
            }
            __syncthreads();

            f32x4 s[4];
#pragma unroll
            for (int nt = 0; nt < 4; nt++) {
                bf16x8 kb0 = *(const bf16x8*)(&Kb[nt * 16 + lr][quad * 8]);
                bf16x8 kb1 = *(const bf16x8*)(&Kb[nt * 16 + lr][32 + quad * 8]);
                f32x4 z = {0.f, 0.f, 0.f, 0.f};
                z = __builtin_amdgcn_mfma_f32_16x16x32_bf16(qa0, kb0, z, 0, 0, 0);
                z = __builtin_amdgcn_mfma_f32_16x16x32_bf16(qa1, kb1, z, 0, 0, 0);
                s[nt] = z;
            }
            const bool diag = (kt == qt);
#pragma unroll
            for (int nt = 0; nt < 4; nt++)
#pragma unroll
                for (int r = 0; r < 4; r++) {
                    float x = s[nt][r] * 0.125f;
                    if (diag && (nt * 16 + lr > w * 16 + quad * 4 + r)) x = -INFINITY;
                    s[nt][r] = x;
                }
            float mx[4], al[4];
#pragma unroll
            for (int r = 0; r < 4; r++) {
                float m = fmaxf(fmaxf(s[0][r], s[1][r]), fmaxf(s[2][r], s[3][r]));
                m = fmaxf(m, __shfl_xor(m, 1));
                m = fmaxf(m, __shfl_xor(m, 2));
                m = fmaxf(m, __shfl_xor(m, 4));
                m = fmaxf(m, __shfl_xor(m, 8));
                mx[r] = m;
            }
#pragma unroll
            for (int r = 0; r < 4; r++) {
                float mnew = fmaxf(m_r[r], mx[r]);
                al[r] = __expf(m_r[r] - mnew);
                m_r[r] = mnew;
            }
#pragma unroll
            for (int nt = 0; nt < 4; nt++)
#pragma unroll
                for (int r = 0; r < 4; r++)
                    s[nt][r] = __expf(s[nt][r] - m_r[r]);
#pragma unroll
            for (int r = 0; r < 4; r++) {
                float t = s[0][r] + s[1][r] + s[2][r] + s[3][r];
                t += __shfl_xor(t, 1);
                t += __shfl_xor(t, 2);
                t += __shfl_xor(t, 4);
                t += __shfl_xor(t, 8);
                l_r[r] = l_r[r] * al[r] + t;
            }
#pragma unroll
            for (int nt = 0; nt < 4; nt++)
#pragma unroll
                for (int r = 0; r < 4; r++)
                    Pb[w][quad * 4 + r][nt * 16 + lr] = (bf16_t)s[nt][r];
            __syncthreads();

#pragma unroll
            for (int nt = 0; nt < 4; nt++)
#pragma unroll
                for (int r = 0; r < 4; r++) Oacc[nt][r] *= al[r];
            bf16x8 pa0 = *(const bf16x8*)(&Pb[w][lr][quad * 8]);
            bf16x8 pa1 = *(const bf16x8*)(&Pb[w][lr][32 + quad * 8]);
#pragma unroll
            for (int nt = 0; nt < 4; nt++) {
                bf16x8 vb0 = *(const bf16x8*)(&Vt[nt * 16 + lr][quad * 8]);
                bf16x8 vb1 = *(const bf16x8*)(&Vt[nt * 16 + lr][32 + quad * 8]);
                Oacc[nt] = __builtin_amdgcn_mfma_f32_16x16x32_bf16(pa0, vb0, Oacc[nt], 0, 0, 0);
                Oacc[nt] = __builtin_amdgcn_mfma_f32_16x16x32_bf16(pa1, vb1, Oacc[nt], 0, 0, 0);
            }
        }

        // epilogue: O / l -> o_ws [B, L, H*HD] bf16
        const int b = bh >> 4, h = bh & 15;
#pragma unroll
        for (int r = 0; r < 4; r++) {
            float inv = 1.0f / l_r[r];
            int q = qt * 64 + w * 16 + quad * 4 + r;
            bf16_t* op = o_ws + ((size_t)(b * LQ + q)) * 1024 + h * 64;
#pragma unroll
            for (int nt = 0; nt < 4; nt++)
                op[nt * 16 + lr] = (bf16_t)(Oacc[nt][r] * inv);
        }
    }
}

// ---------------- launch -----------------------------------------------------
extern "C" void kernel_launch(void* const* d_in, const int* in_sizes, int n_in,
                              void* d_out, int out_size, void* d_ws, size_t ws_size,
                              hipStream_t stream) {
    const float* x        = (const float*)d_in[0];
    const float* rope_cos = (const float*)d_in[1];
    const float* rope_sin = (const float*)d_in[2];
    const float* W_qkv    = (const float*)d_in[3];
    const float* W_out    = (const float*)d_in[4];
    const float* b_out    = (const float*)d_in[5];
    float* out = (float*)d_out;

    // ws layout (float units):
    // [0,4M)   q_ws fp32        [4M,8M)  k_ws fp32      [8M,12M) v_ws fp32
    // [12M,14M) ob   bf16 (4M)  [14M,16M) xb  bf16 (4M)
    // [16M,17.5M) Wqkvt bf16 (3M)  [17.5M,18M) Wot bf16 (1M)    total 72 MB
    float* ws    = (float*)d_ws;
    float* q_ws  = ws;
    float* k_ws  = ws + (size_t)4 * 1024 * 1024;
    float* v_ws  = ws + (size_t)8 * 1024 * 1024;
    bf16_t* ob    = (bf16_t*)(ws + (size_t)12 * 1024 * 1024);
    bf16_t* xb    = (bf16_t*)(ws + (size_t)14 * 1024 * 1024);
    bf16_t* Wqkvt = (bf16_t*)(ws + (size_t)16 * 1024 * 1024);
    bf16_t* Wot   = (bf16_t*)(ws + (size_t)17 * 1024 * 1024 + 512 * 1024);

    // converts / transposes (fp32 -> bf16)
    convert_kernel<<<(4096 * 1024 / 4) / 256, 256, 0, stream>>>(x, xb);
    dim3 gt1(3072 / 32, 1024 / 32);
    transpose_bf16_kernel<<<gt1, 256, 0, stream>>>(W_qkv, Wqkvt, 1024, 3072);
    dim3 gt2(1024 / 32, 1024 / 32);
    transpose_bf16_kernel<<<gt2, 256, 0, stream>>>(W_out, Wot, 1024, 1024);

    // QKV projection (MFMA) -> fp32 q/k/v in [B,H,L,HD]
    dim3 g1(3072 / 128, 4096 / 128);
    mfma_gemm_kernel<0><<<g1, 256, 0, stream>>>(xb, Wqkvt, 4096, 3072, 1024,
                                                q_ws, k_ws, v_ws, nullptr);

    rope_kernel<<<(2 * BQ * HQ * LQ * 32) / 256, 256, 0, stream>>>(q_ws, rope_cos, rope_sin);

    dim3 g2(16, 32);
    attn_mfma_kernel<<<g2, 256, 0, stream>>>(q_ws, k_ws, v_ws, ob);

    // out projection (MFMA) + bias -> fp32 [B*L, D]
    dim3 g3(1024 / 128, 4096 / 128);
    mfma_gemm_kernel<1><<<g3, 256, 0, stream>>>(ob, Wot, 4096, 1024, 1024,
                                                out, nullptr, nullptr, b_out);
}